// Round 1
// 453.195 us; speedup vs baseline: 1.5058x; 1.5058x over previous
//
#include <hip/hip_runtime.h>
#include <cfloat>
#include <math.h>

// Problem constants
#define BQ 8
#define T 2048
#define D 256
#define DAC 36
#define CH 292
#define K 8192
#define NROWS (BQ*T)          // 16384
#define TAU 1e-3f             // single-bf16-pass error bound + np noise
#define FSPLIT 4              // k-splits in fast kernel
#define NKT 16                // (legacy) code-tiles per block
#define RSPLIT 8              // k-splits in rescue (1024 codes each)

// Output offsets (floats, reference return order)
#define OFF_IDX   (BQ*CH*T)
#define OFF_CODES (OFF_IDX + NROWS)
#define OFF_LOSS  (OFF_CODES + BQ*DAC*T)
#define OFF_ACQ   (OFF_LOSS + 1)

// ---------------- MFMA-path ws layout, bytes ----------------
#define WN_C2    0                            // float[K]
#define WN_Z2    32768                        // float[NROWS]
#define WN_CNT   98304
#define WN_LIST  98560                        // int[NROWS]
#define WN_LOSS  164096                       // double[512]
#define WN_WIDX  168192                       // int[NROWS]
#define WN_PMX   262144                       // float4[FSPLIT*NROWS] = 1 MB
#define WN_AZ    1310720                      // ushort[16384][256] = 8 MB (hi only)
#define WN_BC    9699328                      // ushort[8192][256]  = 4 MB (hi only)
#define WN_PR    13893632                     // float2[RSPLIT*NROWS] = 2 MB
#define WN_NEED  15990784

// ---------------- old (fallback) ws layout ----------------
#define WS_C2    0
#define WS_Z2    32768
#define WS_PART  131072
#define WS_IDX   655360
#define WS_LOSS  720896
#define MT 32
#define KT 128
#define DC 32
#define NSPLIT 4

typedef float f32x4 __attribute__((ext_vector_type(4)));
typedef __bf16 bf16x8 __attribute__((ext_vector_type(8)));
typedef __attribute__((address_space(1))) const unsigned int gu32;
typedef __attribute__((address_space(3))) unsigned int lu32;

__device__ inline void gl_lds16(const void* gp, void* lp) {
    __builtin_amdgcn_global_load_lds((gu32*)gp, (lu32*)lp, 16, 0, 0);
}

__device__ inline unsigned short f2bf(float x) {   // RNE, finite inputs
    unsigned u = __float_as_uint(x);
    return (unsigned short)((u + 0x7fffu + ((u >> 16) & 1u)) >> 16);
}

__device__ inline void merge3(float& m1, float& m2, int& mi, float o1, float o2, int oi) {
    if (o1 < m1 || (o1 == m1 && oi < mi)) { m2 = fminf(m1, o2); m1 = o1; mi = oi; }
    else                                  { m2 = fminf(m2, o1); }
}

// ---- numpy pairwise-sum emulation (AVX512 W=16, n=256) ----
template <typename F>
__device__ float np_pairwise256_sq(F ld) {
    float S[2];
    #pragma unroll
    for (int h = 0; h < 2; h++) {
        int base = h * 128;
        float v[16];
        #pragma unroll
        for (int l = 0; l < 16; l++) {
            float q[8];
            #pragma unroll
            for (int j = 0; j < 8; j++) { float x = ld(base + j * 16 + l); q[j] = x * x; }
            v[l] = ((q[0] + q[1]) + (q[2] + q[3])) + ((q[4] + q[5]) + (q[6] + q[7]));
        }
        float t1[8], t2[4], t3[2];
        #pragma unroll
        for (int l = 0; l < 8; l++) t1[l] = v[l] + v[l + 8];
        #pragma unroll
        for (int l = 0; l < 4; l++) t2[l] = t1[l] + t1[l + 4];
        t3[0] = t2[0] + t2[2]; t3[1] = t2[1] + t2[3];
        S[h] = t3[0] + t3[1];
    }
    return S[0] + S[1];
}

// fallback-path helpers
__global__ void k_c2pw(const float* __restrict__ cb, float* __restrict__ c2) {
    int k = blockIdx.x * 256 + threadIdx.x;
    const float* row = cb + (size_t)k * D;
    c2[k] = np_pairwise256_sq([&](int d) { return row[d]; });
}

__global__ void k_z2pw(const float* __restrict__ z, float* __restrict__ z2) {
    int n = blockIdx.x * 256 + threadIdx.x;
    int b = n >> 11, t = n & 2047;
    const float* base = z + (size_t)b * CH * T + t;
    z2[n] = np_pairwise256_sq([&](int d) { return base[(size_t)d * T]; });
}

// ------ prep: Az[n][256] = bf16hi(z) + fused z2 (np pairwise) ---------------
__global__ __launch_bounds__(256) void k_prepz(const float* __restrict__ z,
                                               unsigned short* __restrict__ Az,
                                               float* __restrict__ z2) {
    __shared__ float zt[32][260];
    const int tid = threadIdx.x;
    const int b = blockIdx.x >> 6, t0 = (blockIdx.x & 63) * 32;
    for (int i = tid; i < 2048; i += 256) {
        int d = i >> 3, tq = (i & 7) * 4;
        float4 v = *(const float4*)(z + (size_t)(b * CH + d) * T + t0 + tq);
        zt[tq + 0][d] = v.x; zt[tq + 1][d] = v.y;
        zt[tq + 2][d] = v.z; zt[tq + 3][d] = v.w;
    }
    __syncthreads();
    const int t = tid >> 3, c8 = tid & 7;
    unsigned short* rowp = Az + (size_t)(b * 2048 + t0 + t) * 256;
    #pragma unroll
    for (int li = 0; li < 4; li++) {
        int u = c8 + 8 * li;                 // 16B chunk index 0..31
        int dbase = u * 8;
        float f[8];
        *(float4*)&f[0] = *(float4*)&zt[t][dbase];
        *(float4*)&f[4] = *(float4*)&zt[t][dbase + 4];
        unsigned short h[8];
        #pragma unroll
        for (int e = 0; e < 8; e++) h[e] = f2bf(f[e]);
        *(uint4*)(rowp + u * 8) = *(uint4*)h;
    }
    if (tid < 32)
        z2[b * 2048 + t0 + tid] = np_pairwise256_sq([&](int d) { return zt[tid][d]; });
}

// ------ prep: Bc[k][256] = bf16hi(c) + fused c2 + cnt=0 ---------------------
__global__ void k_prepc(const float* __restrict__ cb, unsigned short* __restrict__ Bc,
                        float* __restrict__ c2, int* __restrict__ cnt) {
    __shared__ float crow[4][260];
    const int tid = threadIdx.x, w = tid >> 6, l = tid & 63;
    const int k = blockIdx.x * 4 + w;
    float4 v = *(const float4*)(cb + (size_t)k * D + l * 4);
    *(float4*)&crow[w][l * 4] = v;
    float fa[4] = {v.x, v.y, v.z, v.w};
    unsigned short hi[4];
    #pragma unroll
    for (int e = 0; e < 4; e++) hi[e] = f2bf(fa[e]);
    *(uint2*)(Bc + (size_t)k * 256 + l * 4) = *(uint2*)hi;
    __syncthreads();
    if (tid < 4) {
        int kk = blockIdx.x * 4 + tid;
        c2[kk] = np_pairwise256_sq([&](int d) { return crow[tid][d]; });
    }
    if (blockIdx.x == 0 && tid == 0) *cnt = 0;
}

// ---------------- MFMA fast argmin: single bf16 pass (register-resident A) --
// Each block: 128 rows x 2048 codes (sp split). Wave w owns rows w*32..w*32+31
// with its A fragments resident in 64 VGPRs (loaded ONCE -- no A re-staging).
// Only B streams through LDS: 64-code tiles (32 KB), double-buffered.
// Per barrier gap: 32 ds_read_b128 + 64 MFMA + epilogue (~1000 cyc) covers the
// 32 KB prefetch latency; waves own disjoint rows -> no cross-wave merge.
__global__ __launch_bounds__(256, 2) void k_fast(
        const unsigned short* __restrict__ Az, const unsigned short* __restrict__ Bc,
        const float* __restrict__ c2g, float4* __restrict__ pmx) {
    __shared__ __align__(16) unsigned char smem8[65536];   // 2 x 32KB B-tile

    const int tid = threadIdx.x;
    const int w = tid >> 6, lane = tid & 63;
    const int quad = lane >> 4, c = lane & 15;

    const int sp = blockIdx.x >> 7;          // split 0..3
    const int nt = blockIdx.x & 127;         // row tile
    const int n0 = nt * 128;
    const int kbase = sp * 2048;

    const char* Azb = (const char*)Az;
    const char* Bcb = (const char*)Bc;

    // stage one 64-code B tile (32 KB): linear LDS dest, inverse-swizzled
    // global source (LDS[code][ch] holds global chunk ch ^ (code&7))
    auto stage = [&](int t, int buf) {
        const int k0 = kbase + t * 64;
        unsigned char* base = smem8 + buf * 32768;
        #pragma unroll
        for (int q = 0; q < 8; q++) {
            const int seg = w * 8 + q;                  // 0..31, wave-uniform
            const int code = seg * 2 + (lane >> 5);     // 2 codes per seg
            const int g = (lane & 31) ^ (code & 7);     // src chunk (involution)
            gl_lds16(Bcb + (size_t)(kbase + t * 64 + code) * 512 + g * 16,
                     base + seg * 1024);
        }
        (void)k0;
    };

    // ---- A fragments: 32 rows/wave resident in VGPRs (64 VGPR) ----
    // af[i][ks]: row = n0 + w*32 + i*16 + c, k-elems ks*32 + quad*8 + 0..7
    bf16x8 af[2][8];
    #pragma unroll
    for (int i = 0; i < 2; i++)
        #pragma unroll
        for (int ks = 0; ks < 8; ks++)
            af[i][ks] = *(const bf16x8*)(Azb +
                (size_t)(n0 + w * 32 + i * 16 + c) * 512 + ks * 64 + quad * 16);

    float bm1[8], bm2[8]; int bid[8];
    #pragma unroll
    for (int sl = 0; sl < 8; sl++) { bm1[sl] = FLT_MAX; bm2[sl] = FLT_MAX; bid[sl] = 0x7fffffff; }

    int cur = 0;
    stage(0, 0);
    for (int t = 0; t < 32; t++) {
        const int k0 = kbase + t * 64;
        __syncthreads();                     // buf[cur] staged (drains prefetch)
        if (t < 31) stage(t + 1, cur ^ 1);   // prefetch overlaps compute below
        float c2v[4];
        #pragma unroll
        for (int j = 0; j < 4; j++) c2v[j] = c2g[k0 + j * 16 + c];

        const unsigned char* base = smem8 + cur * 32768;
        f32x4 acc[2][4];
        #pragma unroll
        for (int i = 0; i < 2; i++)
            #pragma unroll
            for (int j = 0; j < 4; j++) acc[i][j] = (f32x4)0.0f;

        #pragma unroll
        for (int j = 0; j < 4; j++) {
            bf16x8 bf[8];
            #pragma unroll
            for (int ks = 0; ks < 8; ks++)
                bf[ks] = *(const bf16x8*)(base + (j * 16 + c) * 512 +
                                          (((ks * 4 + quad) ^ (lane & 7)) << 4));
            #pragma unroll
            for (int ks = 0; ks < 8; ks++) {   // k ascending: same order as before
                acc[0][j] = __builtin_amdgcn_mfma_f32_16x16x32_bf16(af[0][ks], bf[ks], acc[0][j], 0, 0, 0);
                acc[1][j] = __builtin_amdgcn_mfma_f32_16x16x32_bf16(af[1][ks], bf[ks], acc[1][j], 0, 0, 0);
            }
        }

        // per-tile register epilogue (k ascending -> strict <, first idx)
        #pragma unroll
        for (int j = 0; j < 4; j++) {
            const int kk = k0 + j * 16 + c;
            #pragma unroll
            for (int i = 0; i < 2; i++)
                #pragma unroll
                for (int r = 0; r < 4; r++) {
                    float sc = fmaf(-2.0f, acc[i][j][r], c2v[j]);
                    int sl = i * 4 + r;
                    if (sc < bm1[sl]) { bm2[sl] = bm1[sl]; bm1[sl] = sc; bid[sl] = kk; }
                    else if (sc < bm2[sl]) bm2[sl] = sc;
                }
        }
        cur ^= 1;
    }

    // butterfly over the 16 c-lanes (same quad) -- waves own disjoint rows
    #pragma unroll
    for (int mask = 1; mask <= 8; mask <<= 1)
        #pragma unroll
        for (int sl = 0; sl < 8; sl++) {
            float o1 = __shfl_xor(bm1[sl], mask, 64);
            float o2 = __shfl_xor(bm2[sl], mask, 64);
            int   oi = __shfl_xor(bid[sl], mask, 64);
            merge3(bm1[sl], bm2[sl], bid[sl], o1, o2, oi);
        }
    if (c == 0) {
        #pragma unroll
        for (int i = 0; i < 2; i++)
            #pragma unroll
            for (int r = 0; r < 4; r++) {
                int row = w * 32 + i * 16 + quad * 4 + r, sl = i * 4 + r;
                pmx[(size_t)sp * NROWS + n0 + row] =
                    make_float4(bm1[sl], bm2[sl], __int_as_float(bid[sl]), 0.f);
            }
    }
}

// ---------------- reduce 4 k-splits; flag ambiguous rows ----------------
__global__ void k_reduce2(const float4* __restrict__ pmx, int* __restrict__ widx,
                          int* __restrict__ cnt, int* __restrict__ list,
                          float* __restrict__ out) {
    int n = blockIdx.x * 256 + threadIdx.x;
    float a1 = FLT_MAX, a2 = FLT_MAX; int ai = 0x7fffffff;
    #pragma unroll
    for (int s = 0; s < FSPLIT; s++) {
        float4 p = pmx[(size_t)s * NROWS + n];
        merge3(a1, a2, ai, p.x, p.y, __float_as_int(p.z));
    }
    widx[n] = ai;
    out[OFF_IDX + n] = (float)ai;
    if (a2 - a1 < TAU) { int pos = atomicAdd(cnt, 1); list[pos] = n; }
}

// -------- exact np-pipeline rescue: Round-3 k_exact on compacted rows -------
// 32 flagged rows per group x 8 k-splits of 1024 codes. LDS-tiled codebook
// (32-row reuse per staged byte), d-ascending fmaf chain, (z2-2e)+c2, strict <.
__global__ __launch_bounds__(256) void k_rescuex(
        const float* __restrict__ z, const float* __restrict__ cb,
        const float* __restrict__ c2, const float* __restrict__ z2,
        const int* __restrict__ cnt, const int* __restrict__ list,
        float2* __restrict__ pr) {
    __shared__ float zs[D][MT];       // 32 KB (aliased for reduce at end)
    __shared__ float cs[DC][KT + 4];
    __shared__ int   ls[MT];
    __shared__ float z2sh[MT];
    const int tid = threadIdx.x;
    const int tx = tid & 31, ty = tid >> 5;
    const int grp = blockIdx.x >> 3, sp = blockIdx.x & 7;
    const int cntv = *cnt;
    const int base = grp * MT;
    if (base >= cntv) return;
    const int nr = min(MT, cntv - base);
    const int kbase = sp * (K / RSPLIT);

    if (tid < MT) {
        int pos = base + ((tid < nr) ? tid : (nr - 1));
        int n = list[pos];
        ls[tid] = n;
        z2sh[tid] = z2[n];
    }
    __syncthreads();
    for (int i = tid; i < D * MT; i += 256) {     // gather scattered z rows
        int d = i >> 5, r = i & 31;
        int n = ls[r];
        zs[d][r] = z[((size_t)((n >> 11) * CH + d)) * T + (n & 2047)];
    }
    float z2r[4];
    #pragma unroll
    for (int i = 0; i < 4; i++) z2r[i] = z2sh[ty * 4 + i];

    float m1[4]; int bi[4];
    #pragma unroll
    for (int i = 0; i < 4; i++) { m1[i] = FLT_MAX; bi[i] = 0x7fffffff; }
    for (int ktt = 0; ktt < K / RSPLIT; ktt += KT) {
        const int k0 = kbase + ktt;
        float acc[4][4] = {};
        for (int dc = 0; dc < D; dc += DC) {
            __syncthreads();
            {
                int kl = tid & 127, half = tid >> 7;
                const float4* src = (const float4*)(cb + (size_t)(k0 + kl) * D + dc + half * 16);
                #pragma unroll
                for (int j = 0; j < 4; j++) {
                    float4 v = src[j];
                    int dl = half * 16 + j * 4;
                    cs[dl + 0][kl] = v.x; cs[dl + 1][kl] = v.y;
                    cs[dl + 2][kl] = v.z; cs[dl + 3][kl] = v.w;
                }
            }
            __syncthreads();
            #pragma unroll 8
            for (int d = 0; d < DC; d++) {
                const float4 zf = *(const float4*)&zs[dc + d][ty * 4];
                const float4 cf = *(const float4*)&cs[d][tx * 4];
                const float za[4] = {zf.x, zf.y, zf.z, zf.w};
                const float ca[4] = {cf.x, cf.y, cf.z, cf.w};
                #pragma unroll
                for (int i = 0; i < 4; i++)
                    #pragma unroll
                    for (int j = 0; j < 4; j++)
                        acc[i][j] = fmaf(za[i], ca[j], acc[i][j]);
            }
        }
        #pragma unroll
        for (int j = 0; j < 4; j++) {
            int kk = k0 + tx * 4 + j;
            float c2v = c2[kk];
            #pragma unroll
            for (int i = 0; i < 4; i++) {
                float tpre = z2r[i] - 2.0f * acc[i][j];   // np combine order
                float s = tpre + c2v;
                if (s < m1[i]) { m1[i] = s; bi[i] = kk; } // strict <: first idx
            }
        }
    }
    __syncthreads();
    float* rm1 = (float*)zs;
    int*   rix = (int*)(rm1 + MT * 32);
    #pragma unroll
    for (int i = 0; i < 4; i++) {
        int slot = (ty * 4 + i) * 32 + tx;
        rm1[slot] = m1[i]; rix[slot] = bi[i];
    }
    __syncthreads();
    if (tid < MT) {
        float a1 = FLT_MAX; int ai = 0x7fffffff;
        for (int t = 0; t < 32; t++) {
            float b1 = rm1[tid * 32 + t]; int bidx = rix[tid * 32 + t];
            if (b1 < a1 || (b1 == a1 && bidx < ai)) { a1 = b1; ai = bidx; }
        }
        if (tid < nr)
            pr[(size_t)sp * NROWS + base + tid] = make_float2(a1, __int_as_float(ai));
    }
}

// -------- merge rescue splits (deterministic, split-ascending = k-asc) ------
__global__ void k_unpack(const float2* __restrict__ pr, const int* __restrict__ cnt,
                         const int* __restrict__ list, int* __restrict__ widx,
                         float* __restrict__ out) {
    int pos = blockIdx.x * 256 + threadIdx.x;
    if (pos >= *cnt) return;
    float a1 = FLT_MAX; int ai = 0x7fffffff;
    #pragma unroll
    for (int s = 0; s < RSPLIT; s++) {
        float2 p = pr[(size_t)s * NROWS + pos];
        float v = p.x; int ix = __float_as_int(p.y);
        if (v < a1 || (v == a1 && ix < ai)) { a1 = v; ai = ix; }
    }
    int n = list[pos];
    widx[n] = ai;
    out[OFF_IDX + n] = (float)ai;
}

// ---------------- fallback exact fp32 GEMM-argmin (Round-3, passing) --------
__global__ __launch_bounds__(256) void k_exact(
        const float* __restrict__ z, const float* __restrict__ cb,
        const float* __restrict__ c2, const float* __restrict__ z2,
        float2* __restrict__ part) {
    __shared__ float zs[D][MT];
    __shared__ float cs[DC][KT + 4];
    const int tid = threadIdx.x;
    const int tx = tid & 31, ty = tid >> 5;
    const int n0 = blockIdx.x * MT;
    const int bb = n0 >> 11, t0 = n0 & 2047;
    const int kbase = blockIdx.y * (K / NSPLIT);
    for (int i = tid; i < D * (MT / 4); i += 256) {
        int d = i >> 3, tg = i & 7;
        float4 v = *(const float4*)(z + ((size_t)(bb * CH + d)) * T + t0 + tg * 4);
        *(float4*)&zs[d][tg * 4] = v;
    }
    float z2r[4];
    #pragma unroll
    for (int i = 0; i < 4; i++) z2r[i] = z2[n0 + ty * 4 + i];
    float m1[4]; int bi[4];
    #pragma unroll
    for (int i = 0; i < 4; i++) { m1[i] = FLT_MAX; bi[i] = 0x7fffffff; }
    for (int ktt = 0; ktt < K / NSPLIT; ktt += KT) {
        const int k0 = kbase + ktt;
        float acc[4][4] = {};
        for (int dc = 0; dc < D; dc += DC) {
            __syncthreads();
            {
                int kl = tid & 127, half = tid >> 7;
                const float4* src = (const float4*)(cb + (size_t)(k0 + kl) * D + dc + half * 16);
                #pragma unroll
                for (int j = 0; j < 4; j++) {
                    float4 v = src[j];
                    int dl = half * 16 + j * 4;
                    cs[dl + 0][kl] = v.x; cs[dl + 1][kl] = v.y;
                    cs[dl + 2][kl] = v.z; cs[dl + 3][kl] = v.w;
                }
            }
            __syncthreads();
            #pragma unroll 8
            for (int d = 0; d < DC; d++) {
                const float4 zf = *(const float4*)&zs[dc + d][ty * 4];
                const float4 cf = *(const float4*)&cs[d][tx * 4];
                const float za[4] = {zf.x, zf.y, zf.z, zf.w};
                const float ca[4] = {cf.x, cf.y, cf.z, cf.w};
                #pragma unroll
                for (int i = 0; i < 4; i++)
                    #pragma unroll
                    for (int j = 0; j < 4; j++)
                        acc[i][j] = fmaf(za[i], ca[j], acc[i][j]);
            }
        }
        #pragma unroll
        for (int j = 0; j < 4; j++) {
            int kk = k0 + tx * 4 + j;
            float c2v = c2[kk];
            #pragma unroll
            for (int i = 0; i < 4; i++) {
                float tpre = z2r[i] - 2.0f * acc[i][j];
                float s = tpre + c2v;
                if (s < m1[i]) { m1[i] = s; bi[i] = kk; }
            }
        }
    }
    __syncthreads();
    float* rm1 = (float*)zs;
    int*   rix = (int*)(rm1 + MT * 32);
    #pragma unroll
    for (int i = 0; i < 4; i++) {
        int slot = (ty * 4 + i) * 32 + tx;
        rm1[slot] = m1[i]; rix[slot] = bi[i];
    }
    __syncthreads();
    if (tid < MT) {
        float a1 = FLT_MAX; int ai = 0x7fffffff;
        for (int t = 0; t < 32; t++) {
            float b1 = rm1[tid * 32 + t]; int bidx = rix[tid * 32 + t];
            if (b1 < a1 || (b1 == a1 && bidx < ai)) { a1 = b1; ai = bidx; }
        }
        part[(size_t)(n0 + tid) * NSPLIT + blockIdx.y] = make_float2(a1, __int_as_float(ai));
    }
}

__global__ void k_reduce(const float2* __restrict__ part, int* __restrict__ widx,
                         float* __restrict__ out) {
    int n = blockIdx.x * 256 + threadIdx.x;
    float a1 = FLT_MAX; int ai = 0x7fffffff;
    #pragma unroll
    for (int s = 0; s < NSPLIT; s++) {
        float2 p = part[(size_t)n * NSPLIT + s];
        float b1 = p.x; int bidx = __float_as_int(p.y);
        if (b1 < a1 || (b1 == a1 && bidx < ai)) { a1 = b1; ai = bidx; }
    }
    widx[n] = ai;
    out[OFF_IDX + n] = (float)ai;
}

// ------------- epilogue: gather z_q + loss partials ----------------
__global__ __launch_bounds__(256) void k_episem(
        const float* __restrict__ z, const float* __restrict__ cb,
        const int* __restrict__ widx, float* __restrict__ out, double* __restrict__ lossp) {
    __shared__ int qidx[32];
    __shared__ float qs[32][260];
    __shared__ double wsum[4];
    const int tid = threadIdx.x;
    const int bb = blockIdx.x >> 6;
    const int t0 = (blockIdx.x & 63) * 32;
    if (tid < 32) qidx[tid] = widx[bb * T + t0 + tid];
    __syncthreads();
    for (int i = tid; i < 32 * 64; i += 256) {
        int tl = i >> 6, lanee = i & 63;
        float4 v = *(const float4*)(cb + (size_t)qidx[tl] * D + lanee * 4);
        *(float4*)&qs[tl][lanee * 4] = v;
    }
    __syncthreads();
    double ls = 0.0;
    for (int it = 0; it < 32; it++) {
        int d = it * 8 + (tid >> 5);
        int tl = tid & 31;
        size_t ga = ((size_t)(bb * CH + d)) * T + t0 + tl;
        float q = qs[tl][d];
        float e = q - z[ga];
        out[ga] = q;
        ls += (double)e * (double)e;
    }
    #pragma unroll
    for (int off = 32; off; off >>= 1) ls += __shfl_down(ls, off, 64);
    if ((tid & 63) == 0) wsum[tid >> 6] = ls;
    __syncthreads();
    if (tid == 0) lossp[blockIdx.x] = wsum[0] + wsum[1] + wsum[2] + wsum[3];
}

// ------------- epilogue: ac path + fused loss finalize (block 0) -----------
__global__ void k_epiac(const float* __restrict__ z, const double* __restrict__ lossp,
                        float* __restrict__ out) {
    __shared__ double sm[256];
    int i = (blockIdx.x * 256 + threadIdx.x) * 4;   // grid exact: no early return
    int b = i / (DAC * T);
    int r = i % (DAC * T);
    int d = r / T, t = r % T;
    size_t zoff = ((size_t)(b * CH + 256 + d)) * T + t;
    float4 v = *(const float4*)(z + zoff);
    float r0, r1, r2, r3;
    {
        float t0 = (float)tanh((double)v.x); r0 = rintf(t0 * 10.0f);
        float t1 = (float)tanh((double)v.y); r1 = rintf(t1 * 10.0f);
        float t2 = (float)tanh((double)v.z); r2 = rintf(t2 * 10.0f);
        float t3 = (float)tanh((double)v.w); r3 = rintf(t3 * 10.0f);
    }
    *(float4*)(out + zoff) = make_float4(r0, r1, r2, r3);
    size_t co = OFF_CODES + (size_t)(b * DAC + d) * T + t;
    *(float4*)(out + co) = make_float4(r0 + 10.0f, r1 + 10.0f, r2 + 10.0f, r3 + 10.0f);
    size_t ao = OFF_ACQ + (size_t)(b * DAC + d) * T + t;
    out[ao + 0] = r0; out[ao + 1] = r1; out[ao + 2] = r2; out[ao + 3] = r3;
    if (blockIdx.x == 0) {
        int tid = threadIdx.x;
        sm[tid] = lossp[tid] + lossp[tid + 256];
        __syncthreads();
        for (int off = 128; off; off >>= 1) {
            if (tid < off) sm[tid] += sm[tid + off];
            __syncthreads();
        }
        if (tid == 0) out[OFF_LOSS] = (float)(1.1 * sm[0] / (double)(BQ * D * T));
    }
}

extern "C" void kernel_launch(void* const* d_in, const int* in_sizes, int n_in,
                              void* d_out, int out_size, void* d_ws, size_t ws_size,
                              hipStream_t stream) {
    const float* z  = (const float*)d_in[0];
    const float* cb = (const float*)d_in[1];
    float* out = (float*)d_out;
    char* ws = (char*)d_ws;

    if (ws_size >= (size_t)WN_NEED) {
        float*  c2    = (float*)(ws + WN_C2);
        float*  z2    = (float*)(ws + WN_Z2);
        int*    cnt   = (int*)(ws + WN_CNT);
        int*    list  = (int*)(ws + WN_LIST);
        double* lossp = (double*)(ws + WN_LOSS);
        int*    widx  = (int*)(ws + WN_WIDX);
        float4* pmx   = (float4*)(ws + WN_PMX);
        unsigned short* Az = (unsigned short*)(ws + WN_AZ);
        unsigned short* Bc = (unsigned short*)(ws + WN_BC);
        float2* pr    = (float2*)(ws + WN_PR);

        hipLaunchKernelGGL(k_prepc,   dim3(K / 4),        dim3(256), 0, stream, cb, Bc, c2, cnt);
        hipLaunchKernelGGL(k_prepz,   dim3(512),          dim3(256), 0, stream, z, Az, z2);
        hipLaunchKernelGGL(k_fast,    dim3(128 * FSPLIT), dim3(256), 0, stream, Az, Bc, c2, pmx);
        hipLaunchKernelGGL(k_reduce2, dim3(NROWS / 256),  dim3(256), 0, stream, pmx, widx, cnt, list, out);
        hipLaunchKernelGGL(k_rescuex, dim3((NROWS / MT) * RSPLIT), dim3(256), 0, stream,
                           z, cb, c2, z2, cnt, list, pr);
        hipLaunchKernelGGL(k_unpack,  dim3(NROWS / 256),  dim3(256), 0, stream, pr, cnt, list, widx, out);
        hipLaunchKernelGGL(k_episem,  dim3(BQ * (T / 32)), dim3(256), 0, stream, z, cb, widx, out, lossp);
        hipLaunchKernelGGL(k_epiac,   dim3(BQ * DAC * T / 1024), dim3(256), 0, stream, z, lossp, out);
    } else {
        float*  c2    = (float*)(ws + WS_C2);
        float*  z2    = (float*)(ws + WS_Z2);
        float2* part  = (float2*)(ws + WS_PART);
        int*    widx  = (int*)(ws + WS_IDX);
        double* lossp = (double*)(ws + WS_LOSS);
        hipLaunchKernelGGL(k_c2pw,   dim3(K / 256),            dim3(256), 0, stream, cb, c2);
        hipLaunchKernelGGL(k_z2pw,   dim3(NROWS / 256),        dim3(256), 0, stream, z, z2);
        hipLaunchKernelGGL(k_exact,  dim3(NROWS / MT, NSPLIT), dim3(256), 0, stream, z, cb, c2, z2, part);
        hipLaunchKernelGGL(k_reduce, dim3(NROWS / 256),        dim3(256), 0, stream, part, widx, out);
        hipLaunchKernelGGL(k_episem, dim3(BQ * (T / 32)),      dim3(256), 0, stream, z, cb, widx, out, lossp);
        hipLaunchKernelGGL(k_epiac,  dim3(BQ * DAC * T / 1024), dim3(256), 0, stream, z, lossp, out);
    }
}